// Round 12
// baseline (127.072 us; speedup 1.0000x reference)
//
#include <hip/hip_runtime.h>
#include <math.h>

#define B_ 16
#define L_ 128
#define D_ 768
#define H1_ 770
#define OUT_ 40
#define NPAIRS 3405     // sum over i of min(30, 128-i)
#define NLOG 1540       // logical cols of Y: U(770) || V(770)
#define YSB 1552        // bf16 Y row stride in shorts (16B-aligned rows)
#define VOFFB 776       // V part at +776 shorts (1552 B, 16B-aligned)
#define KPAD 800        // 25 x 32 MFMA k-steps (k >= 770 zero-padded in B/Cv)
#define W1TROWS 1600    // W1T rows padded (zeros in [1540,1600)) for safe staging
#define NKS 25
#define NTILES 252      // 4x4 (i,j) tiles covering the band
#define BSWZ_N (26 * 3 * 512)   // 25 real k-steps + 1 zero step (prefetch pad)

// virtual block ranges
#define NB_X 1536      // X convert: 2048*192 vec4-units / 256
#define NB_W 166       // Bswz (26*3*512) + Cv (3*800), ceil(42336/256)
#define NB_T 1200      // W1T transpose: 50 n-tiles x 24 k-tiles
#define NB_A (NB_X + NB_W + NB_T)
#define NB_B 800       // gemm tiles 25 cols x 32 row-panels
#define NB_C ((NTILES / 2) * 16)   // pair: 126 tile-pairs x 16 batches, 1 wave each

typedef __attribute__((ext_vector_type(8))) short bf16x8;
typedef __attribute__((ext_vector_type(8))) unsigned short u16x8;
typedef __attribute__((ext_vector_type(4))) float f32x4;
typedef __attribute__((ext_vector_type(4))) unsigned int u32x4;

__device__ inline unsigned short f2bf(float f) {
  unsigned int u = __builtin_bit_cast(unsigned int, f);
  u += 0x7fffu + ((u >> 16) & 1u);          // round-to-nearest-even
  return (unsigned short)(u >> 16);
}

#if __has_builtin(__builtin_amdgcn_cvt_pk_bf16_f32)
typedef __attribute__((ext_vector_type(2))) __bf16 bf16x2_t;
__device__ inline unsigned int pack_bf16(float lo, float hi) {
  bf16x2_t r = __builtin_amdgcn_cvt_pk_bf16_f32(lo, hi);
  return __builtin_bit_cast(unsigned int, r);
}
#else
__device__ inline unsigned int pack_bf16(float lo, float hi) {
  return (unsigned int)f2bf(lo) | ((unsigned int)f2bf(hi) << 16);
}
#endif

// async global->LDS, 16B per lane; LDS dest = wave-uniform base + lane*16
typedef const __attribute__((address_space(1))) void* gas_t;
typedef __attribute__((address_space(3))) void* las_t;
__device__ inline void gl2lds16(const void* g, void* l) {
  __builtin_amdgcn_global_load_lds((gas_t)g, (las_t)l, 16, 0, 0);
}

// tile decode: T -> (ti, d); tile = i in [4ti,4ti+4) x j in [4(ti+d),+4)
__device__ inline void tile_decode(int T, int& ti, int& d) {
  if (T < 216) { ti = T / 9; d = T - ti * 9; }
  else {
    int m = T - 216; int r = 24, w = 8;
    while (m >= w) { m -= w; --w; ++r; }
    ti = r; d = m;
  }
}
// row-major rank of an in-band pair (i,j)
__device__ inline int pair_rank(int i, int j) {
  return (i < 99) ? i * 30 + (j - i)
                  : NPAIRS - (128 - i) * (129 - i) / 2 + (j - i);
}

// ---------------------------------------------------------------------------
// Kernel A: prep (X bf16 convert | Bswz/Cv | W1T transpose)  [= R11]
// Cv = ind*w1c only (b1 folded into gemm epilogue), even/odd-split per 8-group.
// ---------------------------------------------------------------------------
__global__ __launch_bounds__(256) void prep_k(
    const float* __restrict__ hidden, const float* __restrict__ W1,
    const float* __restrict__ b1, const float* __restrict__ W2,
    unsigned short* __restrict__ Xb, unsigned short* __restrict__ W1T,
    unsigned short* __restrict__ Bswz, float* __restrict__ Cv)
{
  __shared__ float t[32][33];
  const int u = blockIdx.x;
  const int tid = threadIdx.x;

  if (u < NB_X) {                        // ---- X convert ----
    int idx = u * 256 + tid;
    int m = idx / 192;
    int c = idx - m * 192;
    float4 f = *(const float4*)(hidden + (size_t)(m + (m >> 7) + 1) * D_ + c * 4);
    ushort4 o;
    o.x = f2bf(f.x); o.y = f2bf(f.y); o.z = f2bf(f.z); o.w = f2bf(f.w);
    *(ushort4*)(Xb + (size_t)m * D_ + c * 4) = o;
  } else if (u < NB_X + NB_W) {          // ---- Bswz + Cv ----
    int idx = (u - NB_X) * 256 + tid;
    if (idx < BSWZ_N) {                  // ks=25 block is all zeros (pad)
      int ks = idx / 1536;
      int rem = idx - ks * 1536;
      int f = rem / 512;
      int l = (rem - f * 512) >> 3;
      int e = rem & 7;
      int n = f * 16 + (l & 15);
      int k = ks * 32 + (l >> 4) * 8 + e;
      float v = (n < OUT_ && k < H1_) ? W2[k * OUT_ + n] : 0.f;
      Bswz[idx] = f2bf(v);
    } else if (idx < BSWZ_N + 3 * KPAD) {
      int c = idx - BSWZ_N;
      int tt = c / KPAD, rem = c - tt * KPAD;
      int g = rem >> 3, pos = rem & 7;
      int m = (pos < 4) ? (pos * 2) : ((pos - 4) * 2 + 1);
      int k = g * 8 + m;
      const float* w1c = W1 + 1536 * H1_;
      Cv[c] = (k < H1_) ? ((float)tt * w1c[k]) : 0.f;   // Cv[0] is all zeros
    }
  } else {                               // ---- W1T transpose ----
    int bx = u - NB_X - NB_W;
    const int tx = tid & 31, ty = tid >> 5;
    const int n0 = (bx % 50) * 32, k0 = (bx / 50) * 32;
    #pragma unroll
    for (int r = 0; r < 4; ++r) {
      int k = k0 + ty + r * 8, n = n0 + tx;
      float v = 0.f;
      if (n < H1_)       v = W1[k * H1_ + n];
      else if (n < NLOG) v = W1[(D_ + k) * H1_ + (n - H1_)];
      t[ty + r * 8][tx] = v;
    }
    __syncthreads();
    #pragma unroll
    for (int r = 0; r < 4; ++r) {
      int n = n0 + ty + r * 8, k = k0 + tx;
      W1T[(size_t)n * D_ + k] = f2bf(t[tx][ty + r * 8]);   // n < 1600 always
    }
  }
}

// ---------------------------------------------------------------------------
// Kernel B: Yb = Xb @ W1T^T (bf16), 64x64 tile, BK=128, global_load_lds,
// 16-chunk XOR swizzle, XCD panel swizzle, b1 folded into U-part.  [= R11]
// ---------------------------------------------------------------------------
__global__ __launch_bounds__(256) void gemm_k(
    const unsigned short* __restrict__ Xb, const unsigned short* __restrict__ W1T,
    const float* __restrict__ b1, unsigned short* __restrict__ Yb)
{
  __shared__ unsigned short As[64][128];   // 16 KB
  __shared__ unsigned short Bs[64][128];   // 16 KB
  const int tid = threadIdx.x;
  const int lane = tid & 63, w = tid >> 6;
  const int lm = lane & 15, q = lane >> 4;
  const int xcd = blockIdx.x & 7;
  const int t = blockIdx.x >> 3;                 // 0..99
  const int col0 = (t % 25) * 64;
  const int row0 = (xcd * 4 + t / 25) * 64;      // all 32 panels covered
  const int m0 = (w >> 1) * 32, n0 = (w & 1) * 32;

  const unsigned short* ga4[4];
  const unsigned short* gb4[4];
  #pragma unroll
  for (int i = 0; i < 4; ++i) {
    int srow = w * 16 + 4 * i + (lane >> 4);
    int chunk = (lane & 15) ^ (srow & 15);
    ga4[i] = Xb  + (size_t)(row0 + srow) * D_ + chunk * 8;
    gb4[i] = W1T + (size_t)(col0 + srow) * D_ + chunk * 8;
  }

  f32x4 acc[2][2] = {};

  for (int k0 = 0; k0 < D_; k0 += 128) {
    #pragma unroll
    for (int i = 0; i < 4; ++i) {
      gl2lds16(ga4[i] + k0, &As[w * 16 + 4 * i][0]);
      gl2lds16(gb4[i] + k0, &Bs[w * 16 + 4 * i][0]);
    }
    __syncthreads();
    #pragma unroll
    for (int ks = 0; ks < 4; ++ks) {
      const int cc = (((ks * 4 + q) ^ lm)) * 8;
      bf16x8 a0 = *(const bf16x8*)&As[m0 + lm]     [cc];
      bf16x8 a1 = *(const bf16x8*)&As[m0 + 16 + lm][cc];
      bf16x8 b0 = *(const bf16x8*)&Bs[n0 + lm]     [cc];
      bf16x8 b1v = *(const bf16x8*)&Bs[n0 + 16 + lm][cc];
      acc[0][0] = __builtin_amdgcn_mfma_f32_16x16x32_bf16(a0, b0, acc[0][0], 0, 0, 0);
      acc[0][1] = __builtin_amdgcn_mfma_f32_16x16x32_bf16(a0, b1v, acc[0][1], 0, 0, 0);
      acc[1][0] = __builtin_amdgcn_mfma_f32_16x16x32_bf16(a1, b0, acc[1][0], 0, 0, 0);
      acc[1][1] = __builtin_amdgcn_mfma_f32_16x16x32_bf16(a1, b1v, acc[1][1], 0, 0, 0);
    }
    __syncthreads();
  }

  #pragma unroll
  for (int tj = 0; tj < 2; ++tj) {
    int col = col0 + n0 + tj * 16 + lm;
    if (col >= NLOG) continue;
    float badd = (col < H1_) ? b1[col] : 0.f;
    int pc = (col < H1_) ? col : col + (VOFFB - H1_);
    #pragma unroll
    for (int ti = 0; ti < 2; ++ti) {
      #pragma unroll
      for (int r = 0; r < 4; ++r) {
        int row = row0 + m0 + ti * 16 + q * 4 + r;
        Yb[(size_t)row * YSB + pc] = f2bf(acc[ti][tj][r] + badd);
      }
    }
  }
}

// ---------------------------------------------------------------------------
// Kernel C: pair — one wave per block, TWO 4x4 tiles per wave (same batch):
// B frags load once per k-step and feed 6 independent MFMAs -> B L2 traffic
// halved, 2x MFMA ILP per ks, epilogue amortized. XCD-local batches (u&15).
// U/V prefetch depth 2 per tile, B rotation depth 1 (zero-padded 26th step).
// ---------------------------------------------------------------------------
__global__ __launch_bounds__(64) void pair_k(
    const unsigned short* __restrict__ Yb, const int* __restrict__ spans,
    const unsigned short* __restrict__ Bswz, const float* __restrict__ Cv,
    const float* __restrict__ b2, float* __restrict__ out)
{
  const int tid = threadIdx.x;           // 0..63
  const int u = blockIdx.x;
  const int bb = u & 15;
  const int G = u >> 4;                  // 0..125
  const int lm = tid & 15, q = tid >> 4;
  const int s = spans[2 * bb], e = spans[2 * bb + 1];

  int i0[2], j0[2];
  const unsigned short* uptr[2];
  const unsigned short* vptr[2];
  const float* cptr[2];
  #pragma unroll
  for (int t = 0; t < 2; ++t) {
    int ti, d;
    tile_decode(G * 2 + t, ti, d);
    i0[t] = ti * 4; j0[t] = (ti + d) * 4;
    int ai = i0[t] + (lm & 3);
    int aj = j0[t] + (lm >> 2);
    int ind = (ai == s && aj == e) ? 2 : ((ai >= s && aj <= e) ? 1 : 0);
    uptr[t] = Yb + (size_t)(bb * L_ + ai) * YSB + q * 8;
    vptr[t] = Yb + (size_t)(bb * L_ + aj) * YSB + VOFFB + q * 8;
    cptr[t] = Cv + ind * KPAD + q * 8;
  }
  const unsigned short* bbase = Bswz + tid * 8;

  f32x4 acc[2][3] = {};
  const f32x4 zero = {0.f, 0.f, 0.f, 0.f};

  // pipeline primes: U/V depth 2 per tile, B depth 1
  u16x8 uu0[2], vv0[2], uu1[2], vv1[2];
  #pragma unroll
  for (int t = 0; t < 2; ++t) {
    uu0[t] = *(const u16x8*)(uptr[t]);
    vv0[t] = *(const u16x8*)(vptr[t]);
    uu1[t] = *(const u16x8*)(uptr[t] + 32);
    vv1[t] = *(const u16x8*)(vptr[t] + 32);
  }
  bf16x8 nb0 = *(const bf16x8*)(bbase + 0 * 512);
  bf16x8 nb1 = *(const bf16x8*)(bbase + 1 * 512);
  bf16x8 nb2 = *(const bf16x8*)(bbase + 2 * 512);

  #pragma unroll 5
  for (int ks = 0; ks < NKS; ++ks) {
    const int ko = ks * 32;
    bf16x8 b0 = nb0, b1v = nb1, b2f = nb2;
    nb0 = *(const bf16x8*)(bbase + (size_t)(ks * 3 + 3) * 512);
    nb1 = *(const bf16x8*)(bbase + (size_t)(ks * 3 + 4) * 512);
    nb2 = *(const bf16x8*)(bbase + (size_t)(ks * 3 + 5) * 512);

    #pragma unroll
    for (int t = 0; t < 2; ++t) {
      u16x8 cu = uu0[t], cw = vv0[t];
      uu0[t] = uu1[t]; vv0[t] = vv1[t];
      uu1[t] = *(const u16x8*)(uptr[t] + ko + 64);   // tail: spare row, finite
      vv1[t] = *(const u16x8*)(vptr[t] + ko + 64);

      // packed h: lo = elems {0,2,4,6}, hi = {1,3,5,7} (Cv pre-split)
      u32x4 ud = __builtin_bit_cast(u32x4, cu);
      u32x4 vd = __builtin_bit_cast(u32x4, cw);
      f32x4 slo = __builtin_bit_cast(f32x4, ud << 16)
                + __builtin_bit_cast(f32x4, vd << 16)
                + *(const f32x4*)(cptr[t] + ko);
      f32x4 shi = __builtin_bit_cast(f32x4, ud & 0xffff0000u)
                + __builtin_bit_cast(f32x4, vd & 0xffff0000u)
                + *(const f32x4*)(cptr[t] + ko + 4);
      slo = __builtin_elementwise_max(slo, zero);
      shi = __builtin_elementwise_max(shi, zero);
      u32x4 hp;
      hp[0] = pack_bf16(slo[0], shi[0]);
      hp[1] = pack_bf16(slo[1], shi[1]);
      hp[2] = pack_bf16(slo[2], shi[2]);
      hp[3] = pack_bf16(slo[3], shi[3]);
      bf16x8 a = __builtin_bit_cast(bf16x8, hp);
      acc[t][0] = __builtin_amdgcn_mfma_f32_16x16x32_bf16(a, b0, acc[t][0], 0, 0, 0);
      acc[t][1] = __builtin_amdgcn_mfma_f32_16x16x32_bf16(a, b1v, acc[t][1], 0, 0, 0);
      acc[t][2] = __builtin_amdgcn_mfma_f32_16x16x32_bf16(a, b2f, acc[t][2], 0, 0, 0);
    }
  }

  // epilogue per tile: C/D row p=4q+r -> pair (i0+r, j0+q), col lm.
  const float b2v0 = b2[lm];
  const float b2v1 = b2[16 + lm];
  const float b2v2 = (lm < 8) ? b2[32 + lm] : 0.f;

  #pragma unroll
  for (int t = 0; t < 2; ++t) {
    #pragma unroll
    for (int r = 0; r < 4; ++r) {
      float l0 = acc[t][0][r] + b2v0;
      float l1 = acc[t][1][r] + b2v1;
      float l2 = (lm < 8) ? (acc[t][2][r] + b2v2) : -INFINITY;
      float mx = fmaxf(fmaxf(l0, l1), l2);
      mx = fmaxf(mx, __shfl_xor(mx, 1));
      mx = fmaxf(mx, __shfl_xor(mx, 2));
      mx = fmaxf(mx, __shfl_xor(mx, 4));
      mx = fmaxf(mx, __shfl_xor(mx, 8));
      float sm = expf(l0 - mx) + expf(l1 - mx) + ((lm < 8) ? expf(l2 - mx) : 0.f);
      sm += __shfl_xor(sm, 1);
      sm += __shfl_xor(sm, 2);
      sm += __shfl_xor(sm, 4);
      sm += __shfl_xor(sm, 8);
      float lsd = mx + logf(sm);

      int pi_ = i0[t] + r, pj_ = j0[t] + q;
      if (pj_ >= pi_ && (pj_ - pi_) < 30) {
        float* op = out + ((size_t)bb * NPAIRS + pair_rank(pi_, pj_)) * OUT_;
        op[lm]      = l0 - lsd;
        op[16 + lm] = l1 - lsd;
        if (lm < 8) op[32 + lm] = l2 - lsd;
      }
    }
  }
}

// ---------------------------------------------------------------------------
extern "C" void kernel_launch(void* const* d_in, const int* in_sizes, int n_in,
                              void* d_out, int out_size, void* d_ws, size_t ws_size,
                              hipStream_t stream) {
  const float* hidden = (const float*)d_in[0];   // (16,129,768) f32
  const int*   spans  = (const int*)d_in[1];     // (16,2) i32
  const float* W1 = (const float*)d_in[4];       // (1537,770) f32
  const float* b1 = (const float*)d_in[5];       // (770,)
  const float* W2 = (const float*)d_in[6];       // (770,40)
  const float* b2 = (const float*)d_in[7];       // (40,)
  float* out = (float*)d_out;                    // (16,3405,40) f32

  // workspace layout (256B-aligned slabs). Yb has one spare row: pair_k's
  // V prefetch on the last row overruns by <=112 shorts into poisoned-but-
  // finite space (multiplied by Bswz zero pad or never used).
  char* base = (char*)d_ws;
  size_t off = 0;
  auto take = [&](size_t bytes) {
    char* p = base + off;
    off = (off + bytes + 255) & ~(size_t)255;
    return p;
  };
  unsigned short* Yb   = (unsigned short*)take((size_t)2049 * YSB * 2);     // 6.36 MB
  unsigned short* Xb   = (unsigned short*)take((size_t)2048 * D_ * 2);      // 3.15 MB
  unsigned short* W1T  = (unsigned short*)take((size_t)W1TROWS * D_ * 2);   // 2.46 MB
  unsigned short* Bswz = (unsigned short*)take((size_t)BSWZ_N * 2);         // 79.9 KB
  float*          Cv   = (float*)take((size_t)3 * KPAD * 4);                // 9.6 KB

  prep_k<<<dim3(NB_A), 256, 0, stream>>>(hidden, W1, b1, W2, Xb, W1T, Bswz, Cv);
  gemm_k<<<dim3(NB_B), 256, 0, stream>>>(Xb, W1T, b1, Yb);
  pair_k<<<dim3(NB_C), 64, 0, stream>>>(Yb, spans, Bswz, Cv, b2, out);
}

// Round 13
// 118.698 us; speedup vs baseline: 1.0705x; 1.0705x over previous
//
#include <hip/hip_runtime.h>
#include <math.h>

#define B_ 16
#define L_ 128
#define D_ 768
#define H1_ 770
#define OUT_ 40
#define NPAIRS 3405     // sum over i of min(30, 128-i)
#define NLOG 1540       // logical cols of Y: U(770) || V(770)
#define YSB 1552        // bf16 Y row stride in shorts (16B-aligned rows)
#define VOFFB 776       // V part at +776 shorts (1552 B, 16B-aligned)
#define KPAD 800        // 25 x 32 MFMA k-steps (k >= 770 zero-padded in B/Cv)
#define W1TROWS 1600    // W1T rows padded (zeros in [1540,1600)) for safe staging
#define NKS 25
#define NTILES 252      // 4x4 (i,j) tiles covering the band
#define BSWZ_N (26 * 3 * 512)   // 25 real k-steps + 1 zero step (prefetch pad)

// virtual block ranges
#define NB_X 1536      // X convert: 2048*192 vec4-units / 256
#define NB_W 166       // Bswz (26*3*512) + Cv (3*800), ceil(42336/256)
#define NB_T 1200      // W1T transpose: 50 n-tiles x 24 k-tiles
#define NB_A (NB_X + NB_W + NB_T)
#define NB_B 800       // gemm tiles 25 cols x 32 row-panels
#define NB_C (NTILES * 16)   // pair: 252 tiles x 16 batches, 1 wave each

typedef __attribute__((ext_vector_type(8))) short bf16x8;
typedef __attribute__((ext_vector_type(8))) unsigned short u16x8;
typedef __attribute__((ext_vector_type(4))) float f32x4;
typedef __attribute__((ext_vector_type(4))) unsigned int u32x4;

__device__ inline unsigned short f2bf(float f) {
  unsigned int u = __builtin_bit_cast(unsigned int, f);
  u += 0x7fffu + ((u >> 16) & 1u);          // round-to-nearest-even
  return (unsigned short)(u >> 16);
}
__device__ inline float bf2f(unsigned short x) {
  return __builtin_bit_cast(float, (unsigned int)x << 16);
}

#if __has_builtin(__builtin_amdgcn_cvt_pk_bf16_f32)
typedef __attribute__((ext_vector_type(2))) __bf16 bf16x2_t;
__device__ inline unsigned int pack_bf16(float lo, float hi) {
  bf16x2_t r = __builtin_amdgcn_cvt_pk_bf16_f32(lo, hi);
  return __builtin_bit_cast(unsigned int, r);
}
#else
__device__ inline unsigned int pack_bf16(float lo, float hi) {
  return (unsigned int)f2bf(lo) | ((unsigned int)f2bf(hi) << 16);
}
#endif

// async global->LDS, 16B per lane; LDS dest = wave-uniform base + lane*16
typedef const __attribute__((address_space(1))) void* gas_t;
typedef __attribute__((address_space(3))) void* las_t;
__device__ inline void gl2lds16(const void* g, void* l) {
  __builtin_amdgcn_global_load_lds((gas_t)g, (las_t)l, 16, 0, 0);
}

// tile decode: T -> (ti, d); tile = i in [4ti,4ti+4) x j in [4(ti+d),+4)
__device__ inline void tile_decode(int T, int& ti, int& d) {
  if (T < 216) { ti = T / 9; d = T - ti * 9; }
  else {
    int m = T - 216; int r = 24, w = 8;
    while (m >= w) { m -= w; --w; ++r; }
    ti = r; d = m;
  }
}
// row-major rank of an in-band pair (i,j)
__device__ inline int pair_rank(int i, int j) {
  return (i < 99) ? i * 30 + (j - i)
                  : NPAIRS - (128 - i) * (129 - i) / 2 + (j - i);
}

// ---------------------------------------------------------------------------
// Kernel A: prep (X bf16 convert | Bswz/Cv | W1T transpose)
// ---------------------------------------------------------------------------
__global__ __launch_bounds__(256) void prep_k(
    const float* __restrict__ hidden, const float* __restrict__ W1,
    const float* __restrict__ b1, const float* __restrict__ W2,
    unsigned short* __restrict__ Xb, unsigned short* __restrict__ W1T,
    unsigned short* __restrict__ Bswz, float* __restrict__ Cv)
{
  __shared__ float t[32][33];
  const int u = blockIdx.x;
  const int tid = threadIdx.x;

  if (u < NB_X) {                        // ---- X convert ----
    int idx = u * 256 + tid;
    int m = idx / 192;
    int c = idx - m * 192;
    float4 f = *(const float4*)(hidden + (size_t)(m + (m >> 7) + 1) * D_ + c * 4);
    ushort4 o;
    o.x = f2bf(f.x); o.y = f2bf(f.y); o.z = f2bf(f.z); o.w = f2bf(f.w);
    *(ushort4*)(Xb + (size_t)m * D_ + c * 4) = o;
  } else if (u < NB_X + NB_W) {          // ---- Bswz + Cv ----
    int idx = (u - NB_X) * 256 + tid;
    if (idx < BSWZ_N) {                  // ks=25 block is all zeros (pad)
      int ks = idx / 1536;
      int rem = idx - ks * 1536;
      int f = rem / 512;
      int l = (rem - f * 512) >> 3;
      int e = rem & 7;
      int n = f * 16 + (l & 15);
      int k = ks * 32 + (l >> 4) * 8 + e;
      float v = (n < OUT_ && k < H1_) ? W2[k * OUT_ + n] : 0.f;
      Bswz[idx] = f2bf(v);
    } else if (idx < BSWZ_N + 3 * KPAD) {
      int c = idx - BSWZ_N;
      int tt = c / KPAD, k = c - tt * KPAD;
      const float* w1c = W1 + 1536 * H1_;
      Cv[c] = (k < H1_) ? (b1[k] + (float)tt * w1c[k]) : 0.f;
    }
  } else {                               // ---- W1T transpose ----
    int bx = u - NB_X - NB_W;
    const int tx = tid & 31, ty = tid >> 5;
    const int n0 = (bx % 50) * 32, k0 = (bx / 50) * 32;
    #pragma unroll
    for (int r = 0; r < 4; ++r) {
      int k = k0 + ty + r * 8, n = n0 + tx;
      float v = 0.f;
      if (n < H1_)       v = W1[k * H1_ + n];
      else if (n < NLOG) v = W1[(D_ + k) * H1_ + (n - H1_)];
      t[ty + r * 8][tx] = v;
    }
    __syncthreads();
    #pragma unroll
    for (int r = 0; r < 4; ++r) {
      int n = n0 + ty + r * 8, k = k0 + tx;
      W1T[(size_t)n * D_ + k] = f2bf(t[tx][ty + r * 8]);   // n < 1600 always
    }
  }
}

// ---------------------------------------------------------------------------
// Kernel B: Yb = Xb @ W1T^T (bf16), 64x64 tile, BK=64, global_load_lds,
// XOR chunk swizzle (conflict-free), XCD panel swizzle: block u -> XCD u&7
// works row-panels [4*(u&7), +4) so each XCD's L2 holds A 0.4MB + B 2.4MB.
// ---------------------------------------------------------------------------
__global__ __launch_bounds__(256) void gemm_k(
    const unsigned short* __restrict__ Xb, const unsigned short* __restrict__ W1T,
    unsigned short* __restrict__ Yb)
{
  __shared__ unsigned short As[64][64];
  __shared__ unsigned short Bs[64][64];
  const int tid = threadIdx.x;
  const int lane = tid & 63, w = tid >> 6;
  const int lm = lane & 15, q = lane >> 4;
  const int xcd = blockIdx.x & 7;
  const int t = blockIdx.x >> 3;                 // 0..99
  const int col0 = (t % 25) * 64;
  const int row0 = (xcd * 4 + t / 25) * 64;      // all 32 panels covered
  const int m0 = (w >> 1) * 32, n0 = (w & 1) * 32;

  // staging: wave w owns rows [w*16,+16); lane -> row +l/8, SWIZZLED chunk
  const int srow = w * 16 + (lane >> 3);
  const int schunk = (((lane & 7) ^ ((lane >> 3) & 7))) * 8;
  const unsigned short* ga = Xb  + (size_t)(row0 + srow) * D_ + schunk;
  const unsigned short* gb = W1T + (size_t)(col0 + srow) * D_ + schunk;

  const int xs = lm & 7;                 // read-side xor key (row & 7)

  f32x4 acc[2][2] = {};

  for (int k0 = 0; k0 < D_; k0 += 64) {
    gl2lds16(ga + k0,          &As[w * 16][0]);
    gl2lds16(ga + k0 + 8 * D_, &As[w * 16 + 8][0]);
    gl2lds16(gb + k0,          &Bs[w * 16][0]);
    gl2lds16(gb + k0 + 8 * D_, &Bs[w * 16 + 8][0]);
    __syncthreads();
    #pragma unroll
    for (int ks = 0; ks < 2; ++ks) {
      const int cc = ((ks * 4 + q) ^ xs) * 8;
      bf16x8 a0 = *(const bf16x8*)&As[m0 + lm]     [cc];
      bf16x8 a1 = *(const bf16x8*)&As[m0 + 16 + lm][cc];
      bf16x8 b0 = *(const bf16x8*)&Bs[n0 + lm]     [cc];
      bf16x8 b1 = *(const bf16x8*)&Bs[n0 + 16 + lm][cc];
      acc[0][0] = __builtin_amdgcn_mfma_f32_16x16x32_bf16(a0, b0, acc[0][0], 0, 0, 0);
      acc[0][1] = __builtin_amdgcn_mfma_f32_16x16x32_bf16(a0, b1, acc[0][1], 0, 0, 0);
      acc[1][0] = __builtin_amdgcn_mfma_f32_16x16x32_bf16(a1, b0, acc[1][0], 0, 0, 0);
      acc[1][1] = __builtin_amdgcn_mfma_f32_16x16x32_bf16(a1, b1, acc[1][1], 0, 0, 0);
    }
    __syncthreads();
  }

  // epilogue: C/D layout col=lane&15, row=q*4+r; store bf16
  #pragma unroll
  for (int ti = 0; ti < 2; ++ti) {
    #pragma unroll
    for (int tj = 0; tj < 2; ++tj) {
      int col = col0 + n0 + tj * 16 + lm;
      if (col >= NLOG) continue;
      int pc = (col < H1_) ? col : col + (VOFFB - H1_);
      #pragma unroll
      for (int r = 0; r < 4; ++r) {
        int row = row0 + m0 + ti * 16 + q * 4 + r;
        Yb[(size_t)row * YSB + pc] = f2bf(acc[ti][tj][r]);
      }
    }
  }
}

// ---------------------------------------------------------------------------
// Kernel C: pair — one WAVE per block (64 thr), grid 252 tiles x 16 batches.
// bb = u&15 -> all blocks of batch bb land on XCD bb%8 (round-robin): each
// XCD's L2 holds only 2 batches of Y (0.79MB) + Bswz. U/V prefetch depth 2,
// B-frag rotation depth 1 (Bswz has a zero-padded 26th k-step).
// ---------------------------------------------------------------------------
__global__ __launch_bounds__(64) void pair_k(
    const unsigned short* __restrict__ Yb, const int* __restrict__ spans,
    const unsigned short* __restrict__ Bswz, const float* __restrict__ Cv,
    const float* __restrict__ b2, float* __restrict__ out)
{
  const int tid = threadIdx.x;           // 0..63
  const int u = blockIdx.x;
  const int bb = u & 15;
  const int T = u >> 4;                  // 0..251
  const int lm = tid & 15, q = tid >> 4;

  int ti, d;
  tile_decode(T, ti, d);
  const int i0 = ti * 4, j0 = (ti + d) * 4;

  const int ai = i0 + (lm & 3);
  const int aj = j0 + (lm >> 2);
  const int s = spans[2 * bb], e = spans[2 * bb + 1];
  const int ind = (ai == s && aj == e) ? 2 : ((ai >= s && aj <= e) ? 1 : 0);

  const unsigned short* uptr = Yb + (size_t)(bb * L_ + ai) * YSB + q * 8;
  const unsigned short* vptr = Yb + (size_t)(bb * L_ + aj) * YSB + VOFFB + q * 8;
  const float* cptr = Cv + ind * KPAD + q * 8;
  const unsigned short* bbase = Bswz + tid * 8;

  f32x4 acc0 = {}, acc1 = {}, acc2 = {};

  // pipeline primes: U/V depth 2, B depth 1
  u16x8 uu0 = *(const u16x8*)(uptr);
  u16x8 vv0 = *(const u16x8*)(vptr);
  u16x8 uu1 = *(const u16x8*)(uptr + 32);
  u16x8 vv1 = *(const u16x8*)(vptr + 32);
  bf16x8 nb0 = *(const bf16x8*)(bbase + 0 * 512);
  bf16x8 nb1 = *(const bf16x8*)(bbase + 1 * 512);
  bf16x8 nb2 = *(const bf16x8*)(bbase + 2 * 512);

  #pragma unroll 5
  for (int ks = 0; ks < NKS; ++ks) {
    const int ko = ks * 32;
    u16x8 cu = uu0, cw = vv0;
    uu0 = uu1; vv0 = vv1;
    uu1 = *(const u16x8*)(uptr + ko + 64);   // last overrun lands in spare row
    vv1 = *(const u16x8*)(vptr + ko + 64);
    bf16x8 b0 = nb0, b1v = nb1, b2f = nb2;
    nb0 = *(const bf16x8*)(bbase + (size_t)(ks * 3 + 3) * 512);  // ks=24 reads
    nb1 = *(const bf16x8*)(bbase + (size_t)(ks * 3 + 4) * 512);  // the zero pad
    nb2 = *(const bf16x8*)(bbase + (size_t)(ks * 3 + 5) * 512);
    float4 c0 = *(const float4*)(cptr + ko);
    float4 c1 = *(const float4*)(cptr + ko + 4);
    float h0 = fmaxf(bf2f(cu[0]) + bf2f(cw[0]) + c0.x, 0.f);
    float h1 = fmaxf(bf2f(cu[1]) + bf2f(cw[1]) + c0.y, 0.f);
    float h2 = fmaxf(bf2f(cu[2]) + bf2f(cw[2]) + c0.z, 0.f);
    float h3 = fmaxf(bf2f(cu[3]) + bf2f(cw[3]) + c0.w, 0.f);
    float h4 = fmaxf(bf2f(cu[4]) + bf2f(cw[4]) + c1.x, 0.f);
    float h5 = fmaxf(bf2f(cu[5]) + bf2f(cw[5]) + c1.y, 0.f);
    float h6 = fmaxf(bf2f(cu[6]) + bf2f(cw[6]) + c1.z, 0.f);
    float h7 = fmaxf(bf2f(cu[7]) + bf2f(cw[7]) + c1.w, 0.f);
    u32x4 hp;
    hp[0] = pack_bf16(h0, h1);
    hp[1] = pack_bf16(h2, h3);
    hp[2] = pack_bf16(h4, h5);
    hp[3] = pack_bf16(h6, h7);
    bf16x8 a = __builtin_bit_cast(bf16x8, hp);
    acc0 = __builtin_amdgcn_mfma_f32_16x16x32_bf16(a, b0, acc0, 0, 0, 0);
    acc1 = __builtin_amdgcn_mfma_f32_16x16x32_bf16(a, b1v, acc1, 0, 0, 0);
    acc2 = __builtin_amdgcn_mfma_f32_16x16x32_bf16(a, b2f, acc2, 0, 0, 0);
  }

  // epilogue: C/D row p=4q+r -> pair (i0+r, j0+q), col lm.
  const float b2v0 = b2[lm];
  const float b2v1 = b2[16 + lm];
  const float b2v2 = (lm < 8) ? b2[32 + lm] : 0.f;

  #pragma unroll
  for (int r = 0; r < 4; ++r) {
    float l0 = acc0[r] + b2v0;
    float l1 = acc1[r] + b2v1;
    float l2 = (lm < 8) ? (acc2[r] + b2v2) : -INFINITY;
    float mx = fmaxf(fmaxf(l0, l1), l2);
    mx = fmaxf(mx, __shfl_xor(mx, 1));
    mx = fmaxf(mx, __shfl_xor(mx, 2));
    mx = fmaxf(mx, __shfl_xor(mx, 4));
    mx = fmaxf(mx, __shfl_xor(mx, 8));
    float sm = expf(l0 - mx) + expf(l1 - mx) + ((lm < 8) ? expf(l2 - mx) : 0.f);
    sm += __shfl_xor(sm, 1);
    sm += __shfl_xor(sm, 2);
    sm += __shfl_xor(sm, 4);
    sm += __shfl_xor(sm, 8);
    float lsd = mx + logf(sm);

    int pi_ = i0 + r, pj_ = j0 + q;
    if (pj_ >= pi_ && (pj_ - pi_) < 30) {
      float* op = out + ((size_t)bb * NPAIRS + pair_rank(pi_, pj_)) * OUT_;
      op[lm]      = l0 - lsd;
      op[16 + lm] = l1 - lsd;
      if (lm < 8) op[32 + lm] = l2 - lsd;
    }
  }
}

// ---------------------------------------------------------------------------
extern "C" void kernel_launch(void* const* d_in, const int* in_sizes, int n_in,
                              void* d_out, int out_size, void* d_ws, size_t ws_size,
                              hipStream_t stream) {
  const float* hidden = (const float*)d_in[0];   // (16,129,768) f32
  const int*   spans  = (const int*)d_in[1];     // (16,2) i32
  const float* W1 = (const float*)d_in[4];       // (1537,770) f32
  const float* b1 = (const float*)d_in[5];       // (770,)
  const float* W2 = (const float*)d_in[6];       // (770,40)
  const float* b2 = (const float*)d_in[7];       // (40,)
  float* out = (float*)d_out;                    // (16,3405,40) f32

  // workspace layout (256B-aligned slabs). Yb has one spare row: pair_k's
  // V prefetch on the last row overruns by <=112 shorts into poisoned-but-
  // finite space (multiplied by Bswz zero pad or never used).
  char* base = (char*)d_ws;
  size_t off = 0;
  auto take = [&](size_t bytes) {
    char* p = base + off;
    off = (off + bytes + 255) & ~(size_t)255;
    return p;
  };
  unsigned short* Yb   = (unsigned short*)take((size_t)2049 * YSB * 2);     // 6.36 MB
  unsigned short* Xb   = (unsigned short*)take((size_t)2048 * D_ * 2);      // 3.15 MB
  unsigned short* W1T  = (unsigned short*)take((size_t)W1TROWS * D_ * 2);   // 2.46 MB
  unsigned short* Bswz = (unsigned short*)take((size_t)BSWZ_N * 2);         // 79.9 KB
  float*          Cv   = (float*)take((size_t)3 * KPAD * 4);                // 9.6 KB

  prep_k<<<dim3(NB_A), 256, 0, stream>>>(hidden, W1, b1, W2, Xb, W1T, Bswz, Cv);
  gemm_k<<<dim3(NB_B), 256, 0, stream>>>(Xb, W1T, Yb);
  pair_k<<<dim3(NB_C), 64, 0, stream>>>(Yb, spans, Bswz, Cv, b2, out);
}